// Round 2
// baseline (637.241 us; speedup 1.0000x reference)
//
#include <hip/hip_runtime.h>

// Sinkhorn OT, scaling form, single persistent kernel:
//   K = exp(-C/eps); s0 = 1
//   repeat 40x: r = (1/M) ./ (K s);  s = (1/N) ./ (K^T r)
//   P = diag(r) K diag(s); dist_b = sum(P .* C)
// B=4, M=N=1024, fp32. Output: dist (B floats) then P (B*M*N floats).
//
// Persistent design: 256 blocks (1 per CU, grid == CU count so all
// co-resident), each block holds 16 K-rows + 16 KT-rows in 128 KB LDS.
// Batches sync independently via 64-arrival device-scope atomic barriers
// (80 barriers replace 80 kernel launches at ~2.3 us/launch).

#define MN 1024
#define EPS_INV 10.0f

// ---------------- zero barrier counters + dist accumulators ----------------
__global__ __launch_bounds__(256) void zero_small(unsigned* __restrict__ cnt,
                                                  float* __restrict__ dist,
                                                  int ncnt, int B) {
    int i = blockIdx.x * 256 + threadIdx.x;
    if (i < ncnt) cnt[i] = 0u;
    if (i < B) dist[i] = 0.0f;
}

// ---------------- build K = exp(-10*C) and K^T (tiled transpose) ----------------
// grid: (MN/64, MN/64, B), block: 256
__global__ __launch_bounds__(256) void build_K(const float* __restrict__ C,
                                               float* __restrict__ K,
                                               float* __restrict__ KT) {
    __shared__ float tile[64][65];  // +1 pad: conflict-free transpose read
    const int b  = blockIdx.z;
    const int tr = blockIdx.y * 64;
    const int tc = blockIdx.x * 64;
    const size_t base = (size_t)b * MN * MN;
    const int tx = threadIdx.x & 63;
    const int ty = threadIdx.x >> 6;

#pragma unroll
    for (int stp = 0; stp < 16; ++stp) {
        int row = ty + stp * 4;
        size_t idx = base + (size_t)(tr + row) * MN + tc + tx;
        float k = expf(-EPS_INV * C[idx]);
        K[idx] = k;
        tile[row][tx] = k;
    }
    __syncthreads();
#pragma unroll
    for (int stp = 0; stp < 16; ++stp) {
        int col = ty + stp * 4;
        KT[base + (size_t)(tc + col) * MN + tr + tx] = tile[tx][col];
    }
}

__device__ __forceinline__ float wave_reduce(float v) {
#pragma unroll
    for (int off = 32; off; off >>= 1) v += __shfl_xor(v, off, 64);
    return v;  // total in ALL lanes (butterfly)
}

__device__ __forceinline__ float dot4(float4 a, float4 b) {
    return a.x * b.x + a.y * b.y + a.z * b.z + a.w * b.w;
}

// per-batch barrier: 64 blocks arrive; release on add, acquire fence on exit
__device__ __forceinline__ void batch_barrier(unsigned* mycnt, unsigned target) {
    __syncthreads();  // drains this block's global writes (vmcnt before s_barrier)
    if (threadIdx.x == 0) {
        __hip_atomic_fetch_add(mycnt, 1u, __ATOMIC_RELEASE, __HIP_MEMORY_SCOPE_AGENT);
        while (__hip_atomic_load(mycnt, __ATOMIC_RELAXED, __HIP_MEMORY_SCOPE_AGENT) < target)
            __builtin_amdgcn_s_sleep(1);
        __builtin_amdgcn_fence(__ATOMIC_ACQUIRE, "agent");
    }
    __syncthreads();
}

// ---------------- persistent Sinkhorn loop + fused finalize ----------------
// grid: B*64 blocks (256 for B=4), block: 256 threads (4 waves)
// block owns K rows [16*blk, 16*blk+16) and KT rows [16*blk, 16*blk+16)
__global__ __launch_bounds__(256, 1) void sink_persist(
        const float* __restrict__ K, const float* __restrict__ KT,
        const float* __restrict__ C, float* __restrict__ r, float* __restrict__ s,
        unsigned* __restrict__ cnt, float* __restrict__ P, float* __restrict__ dist) {
    __shared__ float lds[32 * MN];  // 128 KB: [0,16*MN)=K rows, [16*MN,..)=KT rows
    const int blk   = blockIdx.x;
    const int batch = blk >> 6;      // 64 blocks per batch
    const int tid   = threadIdx.x;
    const int wid   = tid >> 6;
    const int lane  = tid & 63;
    const int row0  = blk * 16;      // global row base (same for K and KT)

    // ---- stage 16 K rows + 16 KT rows into LDS (coalesced float4) ----
    {
        const float4* gk  = (const float4*)(K  + (size_t)row0 * MN);
        const float4* gkt = (const float4*)(KT + (size_t)row0 * MN);
        float4* lk  = (float4*)lds;
        float4* lkt = (float4*)(lds + 16 * MN);
        for (int v = tid; v < 16 * MN / 4; v += 256) {
            lk[v]  = gk[v];
            lkt[v] = gkt[v];
        }
    }
    __syncthreads();

    unsigned* mycnt = cnt + batch * 64;          // 256B-spaced counters
    const float* svec = s + (size_t)batch * MN;  // this batch's vector slices
    const float* rvec = r + (size_t)batch * MN;
    const float inv = 1.0f / (float)MN;
    unsigned bar = 0;
    float rv[4];  // this wave's 4 r values (kept for finalize)

    for (int it = 0; it < 40; ++it) {
        // ---- r-phase: r[row] = inv / dot(K[row,:], s)   (s==1 at it==0) ----
        float4 v0, v1, v2, v3;
        if (it == 0) {
            v0 = v1 = v2 = v3 = make_float4(1.f, 1.f, 1.f, 1.f);
        } else {
            const float4* sv4 = (const float4*)svec;
            v0 = sv4[lane]; v1 = sv4[64 + lane]; v2 = sv4[128 + lane]; v3 = sv4[192 + lane];
        }
#pragma unroll
        for (int j = 0; j < 4; ++j) {
            const float4* l4 = (const float4*)(lds + (wid * 4 + j) * MN);
            float acc = dot4(l4[lane], v0) + dot4(l4[64 + lane], v1)
                      + dot4(l4[128 + lane], v2) + dot4(l4[192 + lane], v3);
            acc = wave_reduce(acc);
            rv[j] = inv / acc;
            if (lane == 0) r[row0 + wid * 4 + j] = rv[j];
        }
        batch_barrier(mycnt, 64u * (++bar));

        // ---- s-phase: s[row] = inv / dot(KT[row,:], r) ----
        {
            const float4* rv4 = (const float4*)rvec;
            v0 = rv4[lane]; v1 = rv4[64 + lane]; v2 = rv4[128 + lane]; v3 = rv4[192 + lane];
        }
#pragma unroll
        for (int j = 0; j < 4; ++j) {
            const float4* l4 = (const float4*)(lds + (16 + wid * 4 + j) * MN);
            float acc = dot4(l4[lane], v0) + dot4(l4[64 + lane], v1)
                      + dot4(l4[128 + lane], v2) + dot4(l4[192 + lane], v3);
            acc = wave_reduce(acc);
            if (lane == 0) s[row0 + wid * 4 + j] = inv / acc;
        }
        batch_barrier(mycnt, 64u * (++bar));
    }

    // ---- finalize: P[row,:] = rv * K[row,:] * s ; dist[b] += sum(P .* C) ----
    float4 s0, s1, s2, s3;
    {
        const float4* sv4 = (const float4*)svec;  // final s (post-acquire)
        s0 = sv4[lane]; s1 = sv4[64 + lane]; s2 = sv4[128 + lane]; s3 = sv4[192 + lane];
    }
    float part = 0.f;
#pragma unroll
    for (int j = 0; j < 4; ++j) {
        const int row = row0 + wid * 4 + j;
        const float4* l4 = (const float4*)(lds + (wid * 4 + j) * MN);
        const float4* c4 = (const float4*)(C + (size_t)row * MN);
        float4*       p4 = (float4*)(P + (size_t)row * MN);
        const float rj = rv[j];
        float4 sv[4] = {s0, s1, s2, s3};
#pragma unroll
        for (int c = 0; c < 4; ++c) {
            float4 k  = l4[c * 64 + lane];
            float4 cc = c4[c * 64 + lane];
            float4 pp;
            pp.x = rj * k.x * sv[c].x;
            pp.y = rj * k.y * sv[c].y;
            pp.z = rj * k.z * sv[c].z;
            pp.w = rj * k.w * sv[c].w;
            p4[c * 64 + lane] = pp;
            part += dot4(pp, cc);
        }
    }
    part = wave_reduce(part);
    if (lane == 0) atomicAdd(&dist[batch], part);
}

extern "C" void kernel_launch(void* const* d_in, const int* in_sizes, int n_in,
                              void* d_out, int out_size, void* d_ws, size_t ws_size,
                              hipStream_t stream) {
    const float* C = (const float*)d_in[0];
    const int B = in_sizes[0] / (MN * MN);  // 4

    // ws layout (floats): K [B*MN*MN] | KT [B*MN*MN] | r [B*MN] | s [B*MN] | cnt [B*64 u32]
    float* ws = (float*)d_ws;
    float* K  = ws;
    float* KT = ws + (size_t)B * MN * MN;
    float* r  = ws + (size_t)2 * B * MN * MN;
    float* s  = r + (size_t)B * MN;
    unsigned* cnt = (unsigned*)(s + (size_t)B * MN);

    float* dist = (float*)d_out;       // (B,)
    float* P    = (float*)d_out + B;   // (B, MN, MN)

    zero_small<<<1, 256, 0, stream>>>(cnt, dist, B * 64, B);
    build_K<<<dim3(MN / 64, MN / 64, B), 256, 0, stream>>>(C, K, KT);
    sink_persist<<<B * 64, 256, 0, stream>>>(K, KT, C, r, s, cnt, P, dist);
}

// Round 3
// 403.914 us; speedup vs baseline: 1.5777x; 1.5777x over previous
//
#include <hip/hip_runtime.h>

// Sinkhorn OT, scaling form, persistent kernel with FENCE-FREE device sync:
//   K = exp(-C/eps); s0 = 1
//   repeat 40x: r = (1/M) ./ (K s);  s = (1/N) ./ (K^T r)
//   P = diag(r) K diag(s); dist_b = sum(P .* C)
// B=4, M=N=1024, fp32. Output: dist (B floats) then P (B*M*N floats).
//
// R2 post-mortem: agent-scope acquire/release fences compile to
// buffer_wbl2/buffer_inv (full L2 writeback/invalidate) on gfx950 -> 7 us
// per barrier. R3: all cross-block data moves via relaxed AGENT atomics
// (sc1 coherent ops, no cache maintenance); __syncthreads' vmcnt(0) drain
// gives the release ordering; consumers spin on a per-batch flag.

#define MN 1024
#define EPS_INV 10.0f

// ---------------- zero sync words + dist accumulators ----------------
__global__ __launch_bounds__(256) void zero_small(unsigned* __restrict__ sync,
                                                  float* __restrict__ dist,
                                                  int nsync, int B) {
    int i = blockIdx.x * 256 + threadIdx.x;
    if (i < nsync) sync[i] = 0u;
    if (i < B) dist[i] = 0.0f;
}

// ---------------- build K = exp(-10*C) and K^T (tiled transpose) ----------------
__global__ __launch_bounds__(256) void build_K(const float* __restrict__ C,
                                               float* __restrict__ K,
                                               float* __restrict__ KT) {
    __shared__ float tile[64][65];
    const int b  = blockIdx.z;
    const int tr = blockIdx.y * 64;
    const int tc = blockIdx.x * 64;
    const size_t base = (size_t)b * MN * MN;
    const int tx = threadIdx.x & 63;
    const int ty = threadIdx.x >> 6;

#pragma unroll
    for (int stp = 0; stp < 16; ++stp) {
        int row = ty + stp * 4;
        size_t idx = base + (size_t)(tr + row) * MN + tc + tx;
        float k = expf(-EPS_INV * C[idx]);
        K[idx] = k;
        tile[row][tx] = k;
    }
    __syncthreads();
#pragma unroll
    for (int stp = 0; stp < 16; ++stp) {
        int col = ty + stp * 4;
        KT[base + (size_t)(tc + col) * MN + tr + tx] = tile[tx][col];
    }
}

__device__ __forceinline__ float wave_reduce(float v) {
#pragma unroll
    for (int off = 32; off; off >>= 1) v += __shfl_xor(v, off, 64);
    return v;
}

__device__ __forceinline__ float dot4(float4 a, float4 b) {
    return a.x * b.x + a.y * b.y + a.z * b.z + a.w * b.w;
}

// fence-free per-batch barrier: relaxed agent atomics only (sc1), no wbl2/inv.
// Preceding __syncthreads drains every wave's vmcnt -> sc1 stores are globally
// visible before any arrival.
__device__ __forceinline__ void batch_barrier(unsigned* cnt, unsigned* flag, unsigned bar) {
    __syncthreads();  // compiler emits s_waitcnt vmcnt(0) lgkmcnt(0) + s_barrier
    if (threadIdx.x == 0) {
        __builtin_amdgcn_s_waitcnt(0);  // belt-and-braces drain for this wave
        unsigned old = __hip_atomic_fetch_add(cnt, 1u, __ATOMIC_RELAXED,
                                              __HIP_MEMORY_SCOPE_AGENT);
        if (old == 64u * bar - 1u) {
            __hip_atomic_store(flag, bar, __ATOMIC_RELAXED, __HIP_MEMORY_SCOPE_AGENT);
        } else {
            while (__hip_atomic_load(flag, __ATOMIC_RELAXED,
                                     __HIP_MEMORY_SCOPE_AGENT) < bar)
                __builtin_amdgcn_s_sleep(2);
        }
    }
    __syncthreads();  // also a full compiler memory barrier: no load hoisting
}

// ---------------- persistent Sinkhorn loop + fused finalize ----------------
// grid: B*64 blocks, 256 threads (4 waves). Block owns 16 K-rows + 16 KT-rows
// in 128 KB LDS; 4 KB LDS vector staging buffer for the shared r/s vector.
__global__ __launch_bounds__(256, 1) void sink_persist(
        const float* __restrict__ K, const float* __restrict__ KT,
        const float* __restrict__ C, float* __restrict__ r, float* __restrict__ s,
        unsigned* __restrict__ sync, float* __restrict__ P, float* __restrict__ dist) {
    __shared__ float lds[32 * MN];   // [0,16*MN)=K rows, [16*MN,..)=KT rows
    __shared__ float vlds[MN];       // staged shared vector (4 KB)
    const int blk   = blockIdx.x;
    const int batch = blk >> 6;
    const int tid   = threadIdx.x;
    const int wid   = tid >> 6;
    const int lane  = tid & 63;
    const int row0  = blk * 16;

    // ---- stage 16 K rows + 16 KT rows into LDS ----
    {
        const float4* gk  = (const float4*)(K  + (size_t)row0 * MN);
        const float4* gkt = (const float4*)(KT + (size_t)row0 * MN);
        float4* lk  = (float4*)lds;
        float4* lkt = (float4*)(lds + 16 * MN);
        for (int v = tid; v < 16 * MN / 4; v += 256) {
            lk[v]  = gk[v];
            lkt[v] = gkt[v];
        }
    }
    __syncthreads();

    unsigned* cnt  = sync + batch * 64;            // 256 B apart per batch
    unsigned* flag = sync + 256 + batch * 64;      // separate quiet line
    float* svec = s + (size_t)batch * MN;
    float* rvec = r + (size_t)batch * MN;
    const float inv = 1.0f / (float)MN;
    unsigned bar = 0;
    float rv[4];

    for (int it = 0; it < 40; ++it) {
        // ---- r-phase: r = inv / (K s); s == 1 at it == 0 ----
        float4 v0, v1, v2, v3;
        if (it == 0) {
            v0 = v1 = v2 = v3 = make_float4(1.f, 1.f, 1.f, 1.f);
        } else {
            for (int i = tid; i < MN; i += 256)
                vlds[i] = __hip_atomic_load(svec + i, __ATOMIC_RELAXED,
                                            __HIP_MEMORY_SCOPE_AGENT);
            __syncthreads();
            const float4* sv4 = (const float4*)vlds;
            v0 = sv4[lane]; v1 = sv4[64 + lane]; v2 = sv4[128 + lane]; v3 = sv4[192 + lane];
        }
#pragma unroll
        for (int j = 0; j < 4; ++j) {
            const float4* l4 = (const float4*)(lds + (wid * 4 + j) * MN);
            float acc = dot4(l4[lane], v0) + dot4(l4[64 + lane], v1)
                      + dot4(l4[128 + lane], v2) + dot4(l4[192 + lane], v3);
            acc = wave_reduce(acc);
            rv[j] = inv / acc;
            if (lane == 0)
                __hip_atomic_store(&rvec[(row0 & 1023) + wid * 4 + j], rv[j],
                                   __ATOMIC_RELAXED, __HIP_MEMORY_SCOPE_AGENT);
        }
        batch_barrier(cnt, flag, ++bar);

        // ---- s-phase: s = inv / (K^T r) ----
        for (int i = tid; i < MN; i += 256)
            vlds[i] = __hip_atomic_load(rvec + i, __ATOMIC_RELAXED,
                                        __HIP_MEMORY_SCOPE_AGENT);
        __syncthreads();
        {
            const float4* rv4 = (const float4*)vlds;
            v0 = rv4[lane]; v1 = rv4[64 + lane]; v2 = rv4[128 + lane]; v3 = rv4[192 + lane];
        }
#pragma unroll
        for (int j = 0; j < 4; ++j) {
            const float4* l4 = (const float4*)(lds + (16 + wid * 4 + j) * MN);
            float acc = dot4(l4[lane], v0) + dot4(l4[64 + lane], v1)
                      + dot4(l4[128 + lane], v2) + dot4(l4[192 + lane], v3);
            acc = wave_reduce(acc);
            if (lane == 0)
                __hip_atomic_store(&svec[(row0 & 1023) + wid * 4 + j], inv / acc,
                                   __ATOMIC_RELAXED, __HIP_MEMORY_SCOPE_AGENT);
        }
        batch_barrier(cnt, flag, ++bar);
    }

    // ---- finalize: P[row,:] = rv * K[row,:] * s ; dist[b] += sum(P .* C) ----
    for (int i = tid; i < MN; i += 256)
        vlds[i] = __hip_atomic_load(svec + i, __ATOMIC_RELAXED,
                                    __HIP_MEMORY_SCOPE_AGENT);
    __syncthreads();
    float4 sv[4];
    {
        const float4* sv4 = (const float4*)vlds;
        sv[0] = sv4[lane]; sv[1] = sv4[64 + lane]; sv[2] = sv4[128 + lane]; sv[3] = sv4[192 + lane];
    }
    float part = 0.f;
#pragma unroll
    for (int j = 0; j < 4; ++j) {
        const int row = row0 + wid * 4 + j;
        const float4* l4 = (const float4*)(lds + (wid * 4 + j) * MN);
        const float4* c4 = (const float4*)(C + (size_t)row * MN);
        float4*       p4 = (float4*)(P + (size_t)row * MN);
        const float rj = rv[j];
#pragma unroll
        for (int c = 0; c < 4; ++c) {
            float4 k  = l4[c * 64 + lane];
            float4 cc = c4[c * 64 + lane];
            float4 pp;
            pp.x = rj * k.x * sv[c].x;
            pp.y = rj * k.y * sv[c].y;
            pp.z = rj * k.z * sv[c].z;
            pp.w = rj * k.w * sv[c].w;
            p4[c * 64 + lane] = pp;
            part += dot4(pp, cc);
        }
    }
    part = wave_reduce(part);
    if (lane == 0) atomicAdd(&dist[batch], part);
}

extern "C" void kernel_launch(void* const* d_in, const int* in_sizes, int n_in,
                              void* d_out, int out_size, void* d_ws, size_t ws_size,
                              hipStream_t stream) {
    const float* C = (const float*)d_in[0];
    const int B = in_sizes[0] / (MN * MN);  // 4

    // ws (floats): K [B*MN*MN] | KT [B*MN*MN] | r [B*MN] | s [B*MN] | sync [512 u32]
    float* ws = (float*)d_ws;
    float* K  = ws;
    float* KT = ws + (size_t)B * MN * MN;
    float* r  = ws + (size_t)2 * B * MN * MN;
    float* s  = r + (size_t)B * MN;
    unsigned* sync = (unsigned*)(s + (size_t)B * MN);
    const int nsync = 512;  // cnt[0..255] + flag[256..511]

    float* dist = (float*)d_out;       // (B,)
    float* P    = (float*)d_out + B;   // (B, MN, MN)

    zero_small<<<(nsync + 255) / 256, 256, 0, stream>>>(sync, dist, nsync, B);
    build_K<<<dim3(MN / 64, MN / 64, B), 256, 0, stream>>>(C, K, KT);
    sink_persist<<<B * 64, 256, 0, stream>>>(K, KT, C, r, s, sync, P, dist);
}

// Round 4
// 369.743 us; speedup vs baseline: 1.7235x; 1.0924x over previous
//
#include <hip/hip_runtime.h>

// Sinkhorn OT, scaling form, persistent kernel with PURE-DATAFLOW sync:
//   K = exp(-C/eps); s0 = 1
//   repeat 40x: r = (1/M) ./ (K s);  s = (1/N) ./ (K^T r)
//   P = diag(r) K diag(s); dist_b = sum(P .* C)
// B=4, M=N=1024, fp32. Output: dist (B floats) then P (B*M*N floats).
//
// R3 post-mortem: counter+flag barrier = 3 serial cross-XCD round trips per
// step (arrivals -> flag -> vector read) ~ 4.2 us/step. R4: no barrier at
// all. Each r/s element is a 64-bit word (epoch<<32 | float bits) stored
// with one relaxed AGENT atomic (sc1, no cache maintenance). Consumers spin
// directly on the tagged words they need: one round trip per step.
// Safety: phase k+1 needs ALL of phase k (no block runs >1 phase ahead);
// a block stores its phase-k outputs only after its phase-(k-1) reads are
// done, so one-deep overwrite is race-free. Epochs are monotone (no ABA).

#define MN 1024
#define EPS_INV 10.0f

// ---------------- zero tag arrays + dist accumulators ----------------
__global__ __launch_bounds__(256) void zero_small(unsigned* __restrict__ tags,
                                                  float* __restrict__ dist,
                                                  int ntags_u32, int B) {
    int i = blockIdx.x * 256 + threadIdx.x;
    if (i < ntags_u32) tags[i] = 0u;
    if (i < B) dist[i] = 0.0f;
}

// ---------------- build K = exp(-10*C) and K^T (tiled transpose) ----------------
__global__ __launch_bounds__(256) void build_K(const float* __restrict__ C,
                                               float* __restrict__ K,
                                               float* __restrict__ KT) {
    __shared__ float tile[64][65];
    const int b  = blockIdx.z;
    const int tr = blockIdx.y * 64;
    const int tc = blockIdx.x * 64;
    const size_t base = (size_t)b * MN * MN;
    const int tx = threadIdx.x & 63;
    const int ty = threadIdx.x >> 6;

#pragma unroll
    for (int stp = 0; stp < 16; ++stp) {
        int row = ty + stp * 4;
        size_t idx = base + (size_t)(tr + row) * MN + tc + tx;
        float k = expf(-EPS_INV * C[idx]);
        K[idx] = k;
        tile[row][tx] = k;
    }
    __syncthreads();
#pragma unroll
    for (int stp = 0; stp < 16; ++stp) {
        int col = ty + stp * 4;
        KT[base + (size_t)(tc + col) * MN + tr + tx] = tile[tx][col];
    }
}

__device__ __forceinline__ float wave_reduce(float v) {
#pragma unroll
    for (int off = 32; off; off >>= 1) v += __shfl_xor(v, off, 64);
    return v;
}

__device__ __forceinline__ float dot4(float4 a, float4 b) {
    return a.x * b.x + a.y * b.y + a.z * b.z + a.w * b.w;
}

__device__ __forceinline__ void store_tagged(unsigned long long* tv, int i,
                                             float v, unsigned epoch) {
    unsigned long long w = ((unsigned long long)epoch << 32) |
                           (unsigned long long)__float_as_uint(v);
    __hip_atomic_store(tv + i, w, __ATOMIC_RELAXED, __HIP_MEMORY_SCOPE_AGENT);
}

// spin until all MN elements carry `epoch`; unpack values into vlds.
// Each thread owns 4 elements; loads are issued together, laggards re-polled.
// Leading __syncthreads: all waves must be done READING vlds (prev phase)
// before we overwrite it.
__device__ __forceinline__ void stage_vec(const unsigned long long* __restrict__ tv,
                                          unsigned epoch, float* __restrict__ vlds,
                                          int tid) {
    __syncthreads();
    int  idx[4] = {tid, tid + 256, tid + 512, tid + 768};
    bool ok[4]  = {false, false, false, false};
    for (;;) {
        bool all = true;
#pragma unroll
        for (int c = 0; c < 4; ++c) {
            if (!ok[c]) {
                unsigned long long w = __hip_atomic_load(
                    tv + idx[c], __ATOMIC_RELAXED, __HIP_MEMORY_SCOPE_AGENT);
                if ((unsigned)(w >> 32) == epoch) {
                    ok[c] = true;
                    vlds[idx[c]] = __uint_as_float((unsigned)w);
                } else {
                    all = false;
                }
            }
        }
        if (all) break;
        __builtin_amdgcn_s_sleep(1);
    }
    __syncthreads();
}

// ---------------- persistent Sinkhorn loop + fused finalize ----------------
// grid: B*64 blocks (1 per CU), 256 threads (4 waves).
// Block owns 16 K-rows + 16 KT-rows in 128 KB LDS + 4 KB vector stage.
__global__ __launch_bounds__(256, 1) void sink_persist(
        const float* __restrict__ K, const float* __restrict__ KT,
        const float* __restrict__ C,
        unsigned long long* __restrict__ rtag, unsigned long long* __restrict__ stag,
        float* __restrict__ P, float* __restrict__ dist) {
    __shared__ float lds[32 * MN];   // [0,16*MN)=K rows, [16*MN,..)=KT rows
    __shared__ float vlds[MN];       // staged shared vector (4 KB)
    const int blk   = blockIdx.x;
    const int batch = blk >> 6;
    const int tid   = threadIdx.x;
    const int wid   = tid >> 6;
    const int lane  = tid & 63;
    const int row0  = blk * 16;            // global row base into K/KT/C/P
    const int lrow0 = row0 & (MN - 1);     // row base within the batch

    // ---- stage 16 K rows + 16 KT rows into LDS ----
    {
        const float4* gk  = (const float4*)(K  + (size_t)row0 * MN);
        const float4* gkt = (const float4*)(KT + (size_t)row0 * MN);
        float4* lk  = (float4*)lds;
        float4* lkt = (float4*)(lds + 16 * MN);
        for (int v = tid; v < 16 * MN / 4; v += 256) {
            lk[v]  = gk[v];
            lkt[v] = gkt[v];
        }
    }
    __syncthreads();

    unsigned long long* rtv = rtag + (size_t)batch * MN;
    unsigned long long* stv = stag + (size_t)batch * MN;
    const float inv = 1.0f / (float)MN;
    float rv[4];

    for (int it = 0; it < 40; ++it) {
        // ---- r-phase: r = inv / (K s); s == 1 at it == 0 ----
        float4 v0, v1, v2, v3;
        if (it == 0) {
            v0 = v1 = v2 = v3 = make_float4(1.f, 1.f, 1.f, 1.f);
        } else {
            stage_vec(stv, (unsigned)it, vlds, tid);
            const float4* sv4 = (const float4*)vlds;
            v0 = sv4[lane]; v1 = sv4[64 + lane]; v2 = sv4[128 + lane]; v3 = sv4[192 + lane];
        }
#pragma unroll
        for (int j = 0; j < 4; ++j) {
            const float4* l4 = (const float4*)(lds + (wid * 4 + j) * MN);
            float acc = dot4(l4[lane], v0) + dot4(l4[64 + lane], v1)
                      + dot4(l4[128 + lane], v2) + dot4(l4[192 + lane], v3);
            acc = wave_reduce(acc);
            rv[j] = inv / acc;
            if (lane == 0) store_tagged(rtv, lrow0 + wid * 4 + j, rv[j], (unsigned)(it + 1));
        }

        // ---- s-phase: s = inv / (K^T r) ----
        stage_vec(rtv, (unsigned)(it + 1), vlds, tid);
        {
            const float4* rv4 = (const float4*)vlds;
            v0 = rv4[lane]; v1 = rv4[64 + lane]; v2 = rv4[128 + lane]; v3 = rv4[192 + lane];
        }
#pragma unroll
        for (int j = 0; j < 4; ++j) {
            const float4* l4 = (const float4*)(lds + (16 + wid * 4 + j) * MN);
            float acc = dot4(l4[lane], v0) + dot4(l4[64 + lane], v1)
                      + dot4(l4[128 + lane], v2) + dot4(l4[192 + lane], v3);
            acc = wave_reduce(acc);
            if (lane == 0)
                store_tagged(stv, lrow0 + wid * 4 + j, inv / acc, (unsigned)(it + 1));
        }
    }

    // ---- finalize: P[row,:] = rv * K[row,:] * s ; dist[b] += sum(P .* C) ----
    stage_vec(stv, 40u, vlds, tid);
    float4 sv[4];
    {
        const float4* sv4 = (const float4*)vlds;
        sv[0] = sv4[lane]; sv[1] = sv4[64 + lane];
        sv[2] = sv4[128 + lane]; sv[3] = sv4[192 + lane];
    }
    float part = 0.f;
#pragma unroll
    for (int j = 0; j < 4; ++j) {
        const int row = row0 + wid * 4 + j;
        const float4* l4 = (const float4*)(lds + (wid * 4 + j) * MN);
        const float4* c4 = (const float4*)(C + (size_t)row * MN);
        float4*       p4 = (float4*)(P + (size_t)row * MN);
        const float rj = rv[j];
#pragma unroll
        for (int c = 0; c < 4; ++c) {
            float4 k  = l4[c * 64 + lane];
            float4 cc = c4[c * 64 + lane];
            float4 pp;
            pp.x = rj * k.x * sv[c].x;
            pp.y = rj * k.y * sv[c].y;
            pp.z = rj * k.z * sv[c].z;
            pp.w = rj * k.w * sv[c].w;
            p4[c * 64 + lane] = pp;
            part += dot4(pp, cc);
        }
    }
    part = wave_reduce(part);
    if (lane == 0) atomicAdd(&dist[batch], part);
}

extern "C" void kernel_launch(void* const* d_in, const int* in_sizes, int n_in,
                              void* d_out, int out_size, void* d_ws, size_t ws_size,
                              hipStream_t stream) {
    const float* C = (const float*)d_in[0];
    const int B = in_sizes[0] / (MN * MN);  // 4

    // ws (floats): K [B*MN*MN] | KT [B*MN*MN] | rtag [B*MN u64] | stag [B*MN u64]
    float* ws = (float*)d_ws;
    float* K  = ws;
    float* KT = ws + (size_t)B * MN * MN;
    unsigned long long* rtag = (unsigned long long*)(ws + (size_t)2 * B * MN * MN);
    unsigned long long* stag = rtag + (size_t)B * MN;
    const int ntags_u32 = B * MN * 4;  // both arrays, in u32 units

    float* dist = (float*)d_out;       // (B,)
    float* P    = (float*)d_out + B;   // (B, MN, MN)

    zero_small<<<(ntags_u32 + 255) / 256, 256, 0, stream>>>(
        (unsigned*)rtag, dist, ntags_u32, B);
    build_K<<<dim3(MN / 64, MN / 64, B), 256, 0, stream>>>(C, K, KT);
    sink_persist<<<B * 64, 256, 0, stream>>>(K, KT, C, rtag, stag, P, dist);
}